// Round 1
// baseline (179.482 us; speedup 1.0000x reference)
//
#include <hip/hip_runtime.h>
#include <hip/hip_bf16.h>

// RestrictedNN DAG, fused per-subtree kernel.
// B=4096, N_INP=4096, L0=512 leaf modules (G=8 genes each, H=16),
// L1=64, L2=8 (FAN=8), root 128->16, final 16->1.
//
// Kernel 1: grid (B/TB)*8, block 256. Each block: batch tile of TB=16 rows,
//   one subtree s (x cols [s*512,(s+1)*512)). Computes gene->h0->h1->h2
//   entirely in LDS, writes h2 [B][8][16] fp32 to workspace.
// Kernel 2: root + final dot, writes out [B].

#define TB 16
#define XS_STRIDE 520   // bf16 units per x row (512 + 8 pad; stride%32dw==4 -> bank spread)
#define H0_J 132        // bf16 units per (b, j) h0 block (8*16 + 4 pad)
#define H0_B (8 * H0_J) // 1056 bf16 per b
#define H1_B 132        // fp32 units per b (128 + 4 pad)

__device__ __forceinline__ float sigf(float v) {
    return __builtin_amdgcn_rcpf(1.0f + __expf(-v));
}
__device__ __forceinline__ float bf2f(unsigned short u) {
    unsigned int x = ((unsigned int)u) << 16;
    return __builtin_bit_cast(float, x);
}
__device__ __forceinline__ unsigned short f2bf(float f) {
    unsigned int u = __builtin_bit_cast(unsigned int, f);
    unsigned int r = u + 0x7fffu + ((u >> 16) & 1u);   // round-nearest-even
    return (unsigned short)(r >> 16);
}

__global__ __launch_bounds__(256) void k_tree(
    const float* __restrict__ x, const float* __restrict__ Wg,
    const float* __restrict__ bg, const float* __restrict__ W0,
    const float* __restrict__ W1, const float* __restrict__ W2,
    float* __restrict__ h2ws)
{
    __shared__ unsigned short xs[TB * XS_STRIDE];  // 16640 B
    __shared__ unsigned short h0s[TB * H0_B];      // 33792 B
    __shared__ float h1s[TB * H1_B];               //  8448 B  (total 58880 B)

    const int tid = threadIdx.x;
    const int s   = blockIdx.x & 7;          // subtree == h2 module; == XCD (round-robin)
    const int b0  = (blockIdx.x >> 3) * TB;  // batch tile base

    // ---------- stage x tile (coalesced fp32 reads -> bf16 LDS) ----------
    {
        const float* xbase = x + (size_t)b0 * 4096 + s * 512;
        for (int i = tid; i < TB * 128; i += 256) {
            const int r = i >> 7, c4 = i & 127;
            const float4 v = *(const float4*)(xbase + (size_t)r * 4096 + c4 * 4);
            *(ushort4*)&xs[r * XS_STRIDE + c4 * 4] =
                make_ushort4(f2bf(v.x), f2bf(v.y), f2bf(v.z), f2bf(v.w));
        }
    }
    __syncthreads();

    // ---------- phase A: gene affine + h0 (512 modules of 8->16) ----------
    // thread = (b in low 4 bits -> 16-lane weight broadcast, mq in high 4)
    {
        const int b  = tid & 15;
        const int mq = tid >> 4;   // 0..15, each handles 4 modules
        const unsigned short* xrow = &xs[b * XS_STRIDE];
#pragma unroll
        for (int it = 0; it < 4; ++it) {
            const int ml = mq * 4 + it;       // local module 0..63
            const int m  = s * 64 + ml;       // global leaf module
            const ushort4 xa = *(const ushort4*)&xrow[ml * 8];
            const ushort4 xb = *(const ushort4*)&xrow[ml * 8 + 4];
            const float4 wga = *(const float4*)(Wg + m * 8);
            const float4 wgb = *(const float4*)(Wg + m * 8 + 4);
            const float4 bga = *(const float4*)(bg + m * 8);
            const float4 bgb = *(const float4*)(bg + m * 8 + 4);
            float gene[8];
            gene[0] = fmaf(bf2f(xa.x), wga.x, bga.x);
            gene[1] = fmaf(bf2f(xa.y), wga.y, bga.y);
            gene[2] = fmaf(bf2f(xa.z), wga.z, bga.z);
            gene[3] = fmaf(bf2f(xa.w), wga.w, bga.w);
            gene[4] = fmaf(bf2f(xb.x), wgb.x, bgb.x);
            gene[5] = fmaf(bf2f(xb.y), wgb.y, bgb.y);
            gene[6] = fmaf(bf2f(xb.z), wgb.z, bgb.z);
            gene[7] = fmaf(bf2f(xb.w), wgb.w, bgb.w);

            float acc[16];
#pragma unroll
            for (int h = 0; h < 16; ++h) acc[h] = 0.f;
            const float* w0m = W0 + m * 128;
#pragma unroll
            for (int g = 0; g < 8; ++g) {
                const float gv = gene[g];
                const float4 wa = *(const float4*)(w0m + g * 16);
                const float4 wb = *(const float4*)(w0m + g * 16 + 4);
                const float4 wc = *(const float4*)(w0m + g * 16 + 8);
                const float4 wd = *(const float4*)(w0m + g * 16 + 12);
                acc[0]  = fmaf(gv, wa.x, acc[0]);
                acc[1]  = fmaf(gv, wa.y, acc[1]);
                acc[2]  = fmaf(gv, wa.z, acc[2]);
                acc[3]  = fmaf(gv, wa.w, acc[3]);
                acc[4]  = fmaf(gv, wb.x, acc[4]);
                acc[5]  = fmaf(gv, wb.y, acc[5]);
                acc[6]  = fmaf(gv, wb.z, acc[6]);
                acc[7]  = fmaf(gv, wb.w, acc[7]);
                acc[8]  = fmaf(gv, wc.x, acc[8]);
                acc[9]  = fmaf(gv, wc.y, acc[9]);
                acc[10] = fmaf(gv, wc.z, acc[10]);
                acc[11] = fmaf(gv, wc.w, acc[11]);
                acc[12] = fmaf(gv, wd.x, acc[12]);
                acc[13] = fmaf(gv, wd.y, acc[13]);
                acc[14] = fmaf(gv, wd.z, acc[14]);
                acc[15] = fmaf(gv, wd.w, acc[15]);
            }
            unsigned short* dst = &h0s[b * H0_B + (ml >> 3) * H0_J + (ml & 7) * 16];
            *(ushort4*)(dst + 0)  = make_ushort4(f2bf(sigf(acc[0])),  f2bf(sigf(acc[1])),
                                                 f2bf(sigf(acc[2])),  f2bf(sigf(acc[3])));
            *(ushort4*)(dst + 4)  = make_ushort4(f2bf(sigf(acc[4])),  f2bf(sigf(acc[5])),
                                                 f2bf(sigf(acc[6])),  f2bf(sigf(acc[7])));
            *(ushort4*)(dst + 8)  = make_ushort4(f2bf(sigf(acc[8])),  f2bf(sigf(acc[9])),
                                                 f2bf(sigf(acc[10])), f2bf(sigf(acc[11])));
            *(ushort4*)(dst + 12) = make_ushort4(f2bf(sigf(acc[12])), f2bf(sigf(acc[13])),
                                                 f2bf(sigf(acc[14])), f2bf(sigf(acc[15])));
        }
    }
    __syncthreads();

    // ---------- phase B: h1 (8 modules of 128->16), 4h x 2b register tile ----------
    {
        const int hq = tid & 3;          // h quad
        const int j  = (tid >> 2) & 7;   // local h1 module
        const int bp = tid >> 5;         // 0..7 -> rows bp*2, bp*2+1
        const float* w1 = W1 + (size_t)(s * 8 + j) * 2048 + hq * 4;
        const unsigned short* p0 = &h0s[(bp * 2 + 0) * H0_B + j * H0_J];
        const unsigned short* p1 = &h0s[(bp * 2 + 1) * H0_B + j * H0_J];
        float acc0[4] = {0.f, 0.f, 0.f, 0.f};
        float acc1[4] = {0.f, 0.f, 0.f, 0.f};
#pragma unroll 4
        for (int k4 = 0; k4 < 32; ++k4) {
            const ushort4 ua = *(const ushort4*)&p0[k4 * 4];
            const ushort4 ub = *(const ushort4*)&p1[k4 * 4];
            const float a[4] = {bf2f(ua.x), bf2f(ua.y), bf2f(ua.z), bf2f(ua.w)};
            const float c[4] = {bf2f(ub.x), bf2f(ub.y), bf2f(ub.z), bf2f(ub.w)};
#pragma unroll
            for (int kk = 0; kk < 4; ++kk) {
                const float4 w = *(const float4*)(w1 + (size_t)(k4 * 4 + kk) * 16);
                acc0[0] = fmaf(a[kk], w.x, acc0[0]);
                acc0[1] = fmaf(a[kk], w.y, acc0[1]);
                acc0[2] = fmaf(a[kk], w.z, acc0[2]);
                acc0[3] = fmaf(a[kk], w.w, acc0[3]);
                acc1[0] = fmaf(c[kk], w.x, acc1[0]);
                acc1[1] = fmaf(c[kk], w.y, acc1[1]);
                acc1[2] = fmaf(c[kk], w.z, acc1[2]);
                acc1[3] = fmaf(c[kk], w.w, acc1[3]);
            }
        }
        const float4 o0 = make_float4(sigf(acc0[0]), sigf(acc0[1]), sigf(acc0[2]), sigf(acc0[3]));
        const float4 o1 = make_float4(sigf(acc1[0]), sigf(acc1[1]), sigf(acc1[2]), sigf(acc1[3]));
        *(float4*)&h1s[(bp * 2 + 0) * H1_B + j * 16 + hq * 4] = o0;
        *(float4*)&h1s[(bp * 2 + 1) * H1_B + j * 16 + hq * 4] = o1;
    }
    __syncthreads();

    // ---------- phase C: h2 (this subtree's 128->16), one (b,h) per thread ----------
    {
        const int h = tid & 15;
        const int b = tid >> 4;
        const float* w2 = W2 + s * 2048 + h;
        const float* hp = &h1s[b * H1_B];
        float acc = 0.f;
#pragma unroll 8
        for (int k4 = 0; k4 < 32; ++k4) {
            const float4 hv = *(const float4*)(hp + k4 * 4);
            acc = fmaf(hv.x, w2[(k4 * 4 + 0) * 16], acc);
            acc = fmaf(hv.y, w2[(k4 * 4 + 1) * 16], acc);
            acc = fmaf(hv.z, w2[(k4 * 4 + 2) * 16], acc);
            acc = fmaf(hv.w, w2[(k4 * 4 + 3) * 16], acc);
        }
        h2ws[(size_t)(b0 + b) * 128 + s * 16 + h] = sigf(acc);
    }
}

// ---------- kernel 2: root (128->16, sigmoid) + final dot(16) ----------
__global__ __launch_bounds__(256) void k_root(
    const float* __restrict__ h2ws, const float* __restrict__ W3,
    const float* __restrict__ Wf, float* __restrict__ out)
{
    const int tid = threadIdx.x;
    const int h = tid & 15;
    const int b = blockIdx.x * 16 + (tid >> 4);
    const float* hp = h2ws + (size_t)b * 128;
    float acc = 0.f;
#pragma unroll 8
    for (int k4 = 0; k4 < 32; ++k4) {
        const float4 hv = *(const float4*)(hp + k4 * 4);
        acc = fmaf(hv.x, W3[(k4 * 4 + 0) * 16 + h], acc);
        acc = fmaf(hv.y, W3[(k4 * 4 + 1) * 16 + h], acc);
        acc = fmaf(hv.z, W3[(k4 * 4 + 2) * 16 + h], acc);
        acc = fmaf(hv.w, W3[(k4 * 4 + 3) * 16 + h], acc);
    }
    float v = sigf(acc) * Wf[h];
    v += __shfl_down(v, 8, 16);
    v += __shfl_down(v, 4, 16);
    v += __shfl_down(v, 2, 16);
    v += __shfl_down(v, 1, 16);
    if (h == 0) out[b] = v;
}

extern "C" void kernel_launch(void* const* d_in, const int* in_sizes, int n_in,
                              void* d_out, int out_size, void* d_ws, size_t ws_size,
                              hipStream_t stream) {
    const float* x  = (const float*)d_in[0];
    const float* Wg = (const float*)d_in[1];
    const float* bg = (const float*)d_in[2];
    const float* W0 = (const float*)d_in[3];
    const float* W1 = (const float*)d_in[4];
    const float* W2 = (const float*)d_in[5];
    const float* W3 = (const float*)d_in[6];
    const float* Wf = (const float*)d_in[7];
    float* out = (float*)d_out;
    float* h2  = (float*)d_ws;   // [4096][8][16] fp32 = 2 MB

    k_tree<<<dim3((4096 / TB) * 8), dim3(256), 0, stream>>>(x, Wg, bg, W0, W1, W2, h2);
    k_root<<<dim3(4096 / 16), dim3(256), 0, stream>>>(h2, W3, Wf, out);
}